// Round 8
// baseline (784.420 us; speedup 1.0000x reference)
//
#include <hip/hip_runtime.h>
#include <hip/hip_bf16.h>

#define TSTEPS 64
#define NTOT   8192
#define FDIM   256
#define HDIM   256
#define ROWS   32
#define NTHR   512

typedef __attribute__((ext_vector_type(8))) short bf16x8;
typedef __attribute__((ext_vector_type(4))) float f32x4;

__device__ __forceinline__ short f2bf(float f) {
    union { float f; unsigned u; } v; v.f = f;
    unsigned r = v.u + 0x7FFFu + ((v.u >> 16) & 1u);
    return (short)(r >> 16);
}

// lgkm-only barrier: does NOT drain vmcnt, so global prefetch loads stay in
// flight across it. Single asm block so nothing can be scheduled between the
// waitcnt and the barrier.
__device__ __forceinline__ void bar_lgkm() {
    asm volatile("s_waitcnt lgkmcnt(0)\n\ts_barrier" ::: "memory");
}

// One block (512 thr, 8 waves) owns ROWS=32 rows of N for all T steps.
// Wave w computes output cols [32w, 32w+32).
//
// Register plan (R1-R7 census): allocator grants arch-VGPR = 1024/waves
// per block (8 waves -> 128) regardless of hints; unified file adds 128
// AGPRs on top at 2 waves/SIMD. Weight fragments (128 regs) are pinned
// ONCE into AGPRs via empty "+a" asm (MFMA reads B directly from AGPR,
// ISA sec 10). Arch-VGPR live set drops to ~60 <= 128 -> no spill.
// R6's lesson: the pin must be OUTSIDE the loop ("+a" redefines its
// operands -> in-loop pin forced a full spill/reload every iteration).
__global__ __launch_bounds__(NTHR, 1)
void rnn_ln_fused(const float* __restrict__ X,
                  const float* __restrict__ W_ih,
                  const float* __restrict__ W_hh,
                  const float* __restrict__ b_ih,
                  const float* __restrict__ b_hh,
                  const float* __restrict__ ln_w,
                  const float* __restrict__ ln_b,
                  float* __restrict__ out)
{
    __shared__ char smem[86016];      // 84KB: forces 1 block/CU
    char* xb0 = smem;                 // x tile buf 0 [32][256] bf16, swizzled
    char* xb1 = smem + 16384;         // x tile buf 1
    char* hb0 = smem + 32768;         // h tile buf 0
    char* hb1 = smem + 49152;         // h tile buf 1
    float* psum = (float*)(smem + 65536);          // [32 rows][8 waves][2]
    float* mrs  = (float*)(smem + 65536 + 2048);   // [32 rows][2] (mean, rstd)

    const int tid  = threadIdx.x;
    const int lane = tid & 63;
    const int wv   = tid >> 6;     // wave 0..7
    const int l15  = lane & 15;
    const int l4   = lane >> 4;    // 0..3
    const int n0   = blockIdx.x * ROWS;

    // ---- weight fragments (loaded to VGPR, then pinned to AGPR) ----
    // B-frag mfma_16x16x32: lane holds col=l15, k=l4*8+e within kk*32 chunk
    bf16x8 wih[8][2], whh[8][2];
    #pragma unroll
    for (int kk = 0; kk < 8; ++kk) {
        #pragma unroll
        for (int tc = 0; tc < 2; ++tc) {
            const int wr = wv*32 + tc*16 + l15;   // weight row = output col
            const int wk = kk*32 + l4*8;
            const f32x4* p = (const f32x4*)(W_ih + wr*FDIM + wk);
            const f32x4* q = (const f32x4*)(W_hh + wr*HDIM + wk);
            f32x4 pa = p[0], pb = p[1], qa = q[0], qb = q[1];
            bf16x8 fi, fh;
            #pragma unroll
            for (int e = 0; e < 4; ++e) {
                fi[e]   = f2bf(pa[e]);  fi[e+4] = f2bf(pb[e]);
                fh[e]   = f2bf(qa[e]);  fh[e+4] = f2bf(qb[e]);
            }
            wih[kk][tc] = fi; whh[kk][tc] = fh;
        }
    }
    // ONE-TIME pin into the AGPR class (zero instructions; hard RA
    // constraint). Never re-pinned inside the loop (R6 disaster).
    asm volatile("" : "+a"(wih[0][0]), "+a"(wih[0][1]), "+a"(wih[1][0]), "+a"(wih[1][1]),
                      "+a"(wih[2][0]), "+a"(wih[2][1]), "+a"(wih[3][0]), "+a"(wih[3][1]),
                      "+a"(wih[4][0]), "+a"(wih[4][1]), "+a"(wih[5][0]), "+a"(wih[5][1]),
                      "+a"(wih[6][0]), "+a"(wih[6][1]), "+a"(wih[7][0]), "+a"(wih[7][1]));
    asm volatile("" : "+a"(whh[0][0]), "+a"(whh[0][1]), "+a"(whh[1][0]), "+a"(whh[1][1]),
                      "+a"(whh[2][0]), "+a"(whh[2][1]), "+a"(whh[3][0]), "+a"(whh[3][1]),
                      "+a"(whh[4][0]), "+a"(whh[4][1]), "+a"(whh[5][0]), "+a"(whh[5][1]),
                      "+a"(whh[6][0]), "+a"(whh[6][1]), "+a"(whh[7][0]), "+a"(whh[7][1]));

    float bc[2], lw[2], lb[2];
    #pragma unroll
    for (int tc = 0; tc < 2; ++tc) {
        const int c = wv*32 + tc*16 + l15;
        bc[tc] = b_ih[c] + b_hh[c];
        lw[tc] = ln_w[c];
        lb[tc] = ln_b[c];
    }

    f32x4 acc[2][2];   // [row-tile][col-tile]; C: col=l15, row=l4*4+j (+16*tr)
    f32x4 xld[4];      // staged X tile (f32), prefetched ahead of LDS

    auto load_x = [&](int t) {
        const f32x4* base = (const f32x4*)(X + ((size_t)t * NTOT + n0) * FDIM);
        #pragma unroll
        for (int k = 0; k < 4; ++k) xld[k] = base[k*512 + tid];  // coalesced
    };
    auto store_x = [&](char* xbuf) {  // row = 8k+wv, col-byte = lane*8; swizzled
        #pragma unroll
        for (int k = 0; k < 4; ++k) {
            const int row = 8*k + wv;
            int off = row*512 + lane*8;
            off ^= (row & 7) << 4;
            unsigned lo = (unsigned)(unsigned short)f2bf(xld[k].x) |
                          ((unsigned)(unsigned short)f2bf(xld[k].y) << 16);
            unsigned hi = (unsigned)(unsigned short)f2bf(xld[k].z) |
                          ((unsigned)(unsigned short)f2bf(xld[k].w) << 16);
            uint2 v; v.x = lo; v.y = hi;
            *(uint2*)(xbuf + off) = v;
        }
    };
    auto mm = [&](const char* buf, const bf16x8 (&wf)[8][2]) {
        #pragma unroll
        for (int kk = 0; kk < 8; ++kk) {
            const int co = kk*64 + l4*16;
            const int r0 = l15, r1 = l15 + 16;
            const int sw = (l15 & 7) << 4;          // r0&7 == r1&7
            bf16x8 a0 = *(const bf16x8*)(buf + ((r0*512 + co) ^ sw));
            bf16x8 a1 = *(const bf16x8*)(buf + ((r1*512 + co) ^ sw));
            #pragma unroll
            for (int tc = 0; tc < 2; ++tc) {
                acc[0][tc] = __builtin_amdgcn_mfma_f32_16x16x32_bf16(a0, wf[kk][tc], acc[0][tc], 0, 0, 0);
                acc[1][tc] = __builtin_amdgcn_mfma_f32_16x16x32_bf16(a1, wf[kk][tc], acc[1][tc], 0, 0, 0);
            }
        }
    };
    auto zero_acc = [&]() {
        #pragma unroll
        for (int tr = 0; tr < 2; ++tr)
            #pragma unroll
            for (int tc = 0; tc < 2; ++tc) acc[tr][tc] = f32x4{0.f, 0.f, 0.f, 0.f};
    };
    auto write_h = [&](char* hbuf, bool addbias) {
        #pragma unroll
        for (int tr = 0; tr < 2; ++tr)
            #pragma unroll
            for (int j = 0; j < 4; ++j) {
                const int row = tr*16 + l4*4 + j;
                const int rs = row*512, sw = (row & 7) << 4;
                #pragma unroll
                for (int tc = 0; tc < 2; ++tc) {
                    const int col = wv*32 + tc*16 + l15;
                    float v = acc[tr][tc][j];
                    if (addbias) v += bc[tc];
                    *(short*)(hbuf + ((rs + col*2) ^ sw)) = f2bf(v);
                }
            }
    };

    // ================= prologue =================
    load_x(0);
    store_x(xb0);                 // x_0 -> xb0
    load_x(1);
    bar_lgkm();

    zero_acc();
    mm(xb0, wih);                 // acc = xw_0
    store_x(xb1);                 // x_1 -> xb1
    load_x(2);                    // xld = x_2
    write_h(hb0, true);           // h0 = xw_0 + b_ih + b_hh (no relu)
    bar_lgkm();

    // ================= main loop =================
    // entry invariants: hb[t&1]=c_t, acc=xw_t, xb[(t+1)&1]=x_{t+1} (t<63),
    //                   xld=x_{t+2} (t<62)
    #pragma unroll 1
    for (int t = 0; t < TSTEPS; ++t) {
        char* hcur = (t & 1) ? hb1 : hb0;
        char* hnxt = (t & 1) ? hb0 : hb1;
        char* xrd  = (t & 1) ? xb0 : xb1;   // x_{t+1}
        char* xwr  = (t & 1) ? xb1 : xb0;   // dest for x_{t+2}

        mm(hcur, whh);                       // acc = xw_t + c_t W_hh^T

        // c_{t+1} = relu(acc + bc)
        #pragma unroll
        for (int tr = 0; tr < 2; ++tr)
            #pragma unroll
            for (int tc = 0; tc < 2; ++tc) {
                f32x4 v = acc[tr][tc];
                #pragma unroll
                for (int j = 0; j < 4; ++j) v[j] = fmaxf(v[j] + bc[tc], 0.f);
                acc[tr][tc] = v;
            }

        // LN partials over this wave's 32 cols -> psum[row][wv]
        {
            float s[8], q[8];
            #pragma unroll
            for (int tr = 0; tr < 2; ++tr)
                #pragma unroll
                for (int j = 0; j < 4; ++j) {
                    float a = acc[tr][0][j] + acc[tr][1][j];
                    float b = acc[tr][0][j]*acc[tr][0][j] + acc[tr][1][j]*acc[tr][1][j];
                    s[tr*4+j] = a; q[tr*4+j] = b;
                }
            #pragma unroll
            for (int m = 1; m < 16; m <<= 1) {
                #pragma unroll
                for (int i = 0; i < 8; ++i) {
                    s[i] += __shfl_xor(s[i], m);
                    q[i] += __shfl_xor(q[i], m);
                }
            }
            if (l15 == 0) {
                #pragma unroll
                for (int tr = 0; tr < 2; ++tr)
                    #pragma unroll
                    for (int j = 0; j < 4; ++j) {
                        const int row = tr*16 + l4*4 + j;
                        float2 w; w.x = s[tr*4+j]; w.y = q[tr*4+j];
                        *(float2*)(psum + (row*8 + wv)*2) = w;
                    }
            }
        }

        if (t < 63) write_h(hnxt, false);    // c_{t+1} -> other h buffer

        bar_lgkm();                          // (A) psum + hnxt visible

        // parallel LN finalize: 8 lanes per row, waves 0-3
        if (tid < 256) {
            const int row = tid >> 3, p = tid & 7;
            const float2 v = *(const float2*)(psum + (row*8 + p)*2);
            float S = v.x, Q = v.y;
            S += __shfl_xor(S, 1); Q += __shfl_xor(Q, 1);
            S += __shfl_xor(S, 2); Q += __shfl_xor(Q, 2);
            S += __shfl_xor(S, 4); Q += __shfl_xor(Q, 4);
            if (p == 0) {
                const float mean = S * (1.f/256.f);
                const float var  = Q * (1.f/256.f) - mean * mean;
                float2 w; w.x = mean; w.y = rsqrtf(var + 1e-5f);
                *(float2*)(mrs + row*2) = w;
            }
        }
        if (t < 62) store_x(xwr);            // x_{t+2} -> xwr

        bar_lgkm();                          // (B) mrs visible; xwr staged

        if (t < 61) load_x(t + 3);           // issue next prefetch ASAP

        // normalize + store out[t]
        float* op = out + ((size_t)t * NTOT + n0) * HDIM;
        #pragma unroll
        for (int tr = 0; tr < 2; ++tr)
            #pragma unroll
            for (int j = 0; j < 4; ++j) {
                const int row = tr*16 + l4*4 + j;
                const float2 ms = *(const float2*)(mrs + row*2);
                #pragma unroll
                for (int tc = 0; tc < 2; ++tc) {
                    const int col = wv*32 + tc*16 + l15;
                    op[row*HDIM + col] = (acc[tr][tc][j] - ms.x) * ms.y * lw[tc] + lb[tc];
                }
            }

        if (t < 63) {
            zero_acc();
            mm(xrd, wih);                    // acc = xw_{t+1}
        }
    }
}

extern "C" void kernel_launch(void* const* d_in, const int* in_sizes, int n_in,
                              void* d_out, int out_size, void* d_ws, size_t ws_size,
                              hipStream_t stream) {
    const float* X   = (const float*)d_in[0];
    const float* Wih = (const float*)d_in[1];
    const float* Whh = (const float*)d_in[2];
    const float* bih = (const float*)d_in[3];
    const float* bhh = (const float*)d_in[4];
    const float* lnw = (const float*)d_in[5];
    const float* lnb = (const float*)d_in[6];
    float* out = (float*)d_out;

    rnn_ln_fused<<<dim3(NTOT / ROWS), dim3(NTHR), 0, stream>>>(
        X, Wih, Whh, bih, bhh, lnw, lnb, out);
}

// Round 9
// 462.149 us; speedup vs baseline: 1.6973x; 1.6973x over previous
//
#include <hip/hip_runtime.h>
#include <hip/hip_bf16.h>

#define TSTEPS 64
#define NTOT   8192
#define FDIM   256
#define HDIM   256
#define ROWS   16
#define NTHR   256

typedef __attribute__((ext_vector_type(8))) short bf16x8;
typedef __attribute__((ext_vector_type(4))) float f32x4;

__device__ __forceinline__ short f2bf(float f) {
    union { float f; unsigned u; } v; v.f = f;
    unsigned r = v.u + 0x7FFFu + ((v.u >> 16) & 1u);
    return (short)(r >> 16);
}

// lgkm-only barrier: does NOT drain vmcnt -> global prefetch loads stay in
// flight across it. Single asm block: nothing schedulable between the
// waitcnt and the barrier.
__device__ __forceinline__ void bar_lgkm() {
    asm volatile("s_waitcnt lgkmcnt(0)\n\ts_barrier" ::: "memory");
}

// R1-R8 register-allocator census: arch-VGPR budget = 1024/waves-per-block,
// immune to launch_bounds/waves_per_eu/LDS pressure. Only the 4-wave block
// (256 regs + compiler-managed AGPR overflow on the unified file) holds the
// ~300-reg weight-resident live set with ZERO spill traffic (R1: FETCH 287MB,
// ideal). Explicit "+a" pins backfire (R6/R8). So: 4-wave blocks, ROWS=16,
// 512 blocks -> 2 blocks/CU co-resident (34KB LDS) for cross-block latency
// overlap, lgkm-only barriers (2/step), parallel LN finalize.
__global__ __launch_bounds__(NTHR, 1)
void rnn_ln_fused(const float* __restrict__ X,
                  const float* __restrict__ W_ih,
                  const float* __restrict__ W_hh,
                  const float* __restrict__ b_ih,
                  const float* __restrict__ b_hh,
                  const float* __restrict__ ln_w,
                  const float* __restrict__ ln_b,
                  float* __restrict__ out)
{
    __shared__ char smem[4*8192 + 512 + 128];
    char* xb0 = smem;                 // x tile buf 0 [16][256] bf16, swizzled
    char* xb1 = smem + 8192;          // x tile buf 1
    char* hb0 = smem + 16384;         // h tile buf 0
    char* hb1 = smem + 24576;         // h tile buf 1
    float* psum = (float*)(smem + 32768);        // [16 rows][4 waves][2]
    float* mrs  = (float*)(smem + 32768 + 512);  // [16 rows][2] (mean, rstd)

    const int tid  = threadIdx.x;
    const int lane = tid & 63;
    const int wv   = tid >> 6;     // wave 0..3
    const int l15  = lane & 15;
    const int l4   = lane >> 4;    // 0..3
    const int n0   = blockIdx.x * ROWS;

    // ---- weight fragments into registers (once); wave owns 64 cols ----
    // B-frag mfma_16x16x32: lane holds col=l15, k=l4*8+e within kk*32 chunk
    bf16x8 wih[8][4], whh[8][4];
    #pragma unroll
    for (int kk = 0; kk < 8; ++kk) {
        #pragma unroll
        for (int tc = 0; tc < 4; ++tc) {
            const int wr = wv*64 + tc*16 + l15;   // weight row = output col
            const int wk = kk*32 + l4*8;
            const f32x4* p = (const f32x4*)(W_ih + wr*FDIM + wk);
            const f32x4* q = (const f32x4*)(W_hh + wr*HDIM + wk);
            f32x4 pa = p[0], pb = p[1], qa = q[0], qb = q[1];
            bf16x8 fi, fh;
            #pragma unroll
            for (int e = 0; e < 4; ++e) {
                fi[e]   = f2bf(pa[e]);  fi[e+4] = f2bf(pb[e]);
                fh[e]   = f2bf(qa[e]);  fh[e+4] = f2bf(qb[e]);
            }
            wih[kk][tc] = fi; whh[kk][tc] = fh;
        }
    }

    float bc[4], lw[4], lb[4];
    #pragma unroll
    for (int tc = 0; tc < 4; ++tc) {
        const int c = wv*64 + tc*16 + l15;
        bc[tc] = b_ih[c] + b_hh[c];
        lw[tc] = ln_w[c];
        lb[tc] = ln_b[c];
    }

    f32x4 acc[4];      // [col-tile]; C: col=wv*64+tc*16+l15, row=l4*4+j
    f32x4 xld[4];      // staged X tile (f32), prefetched ahead of LDS

    auto load_x = [&](int t) {
        const f32x4* base = (const f32x4*)(X + ((size_t)t * NTOT + n0) * FDIM);
        #pragma unroll
        for (int k = 0; k < 4; ++k) xld[k] = base[k*256 + tid];  // coalesced
    };
    auto store_x = [&](char* xbuf) {  // row = 4k+wv, col-byte = lane*8; swizzled
        #pragma unroll
        for (int k = 0; k < 4; ++k) {
            const int row = 4*k + wv;
            int off = row*512 + lane*8;
            off ^= (row & 7) << 4;
            unsigned lo = (unsigned)(unsigned short)f2bf(xld[k].x) |
                          ((unsigned)(unsigned short)f2bf(xld[k].y) << 16);
            unsigned hi = (unsigned)(unsigned short)f2bf(xld[k].z) |
                          ((unsigned)(unsigned short)f2bf(xld[k].w) << 16);
            uint2 v; v.x = lo; v.y = hi;
            *(uint2*)(xbuf + off) = v;
        }
    };
    auto mm = [&](const char* buf, const bf16x8 (&wf)[8][4]) {
        #pragma unroll
        for (int kk = 0; kk < 8; ++kk) {
            const int co = kk*64 + l4*16;
            const int sw = (l15 & 7) << 4;
            bf16x8 a0 = *(const bf16x8*)(buf + ((l15*512 + co) ^ sw));
            #pragma unroll
            for (int tc = 0; tc < 4; ++tc)
                acc[tc] = __builtin_amdgcn_mfma_f32_16x16x32_bf16(a0, wf[kk][tc], acc[tc], 0, 0, 0);
        }
    };
    auto zero_acc = [&]() {
        #pragma unroll
        for (int tc = 0; tc < 4; ++tc) acc[tc] = f32x4{0.f, 0.f, 0.f, 0.f};
    };
    auto write_h = [&](char* hbuf, bool addbias) {
        #pragma unroll
        for (int j = 0; j < 4; ++j) {
            const int row = l4*4 + j;
            const int rs = row*512, sw = (row & 7) << 4;
            #pragma unroll
            for (int tc = 0; tc < 4; ++tc) {
                const int col = wv*64 + tc*16 + l15;
                float v = acc[tc][j];
                if (addbias) v += bc[tc];
                *(short*)(hbuf + ((rs + col*2) ^ sw)) = f2bf(v);
            }
        }
    };

    // ================= prologue =================
    load_x(0);
    store_x(xb0);                 // x_0 -> xb0
    load_x(1);
    bar_lgkm();

    zero_acc();
    mm(xb0, wih);                 // acc = xw_0
    store_x(xb1);                 // x_1 -> xb1
    load_x(2);                    // xld = x_2
    write_h(hb0, true);           // h0 = xw_0 + b_ih + b_hh (no relu)
    bar_lgkm();

    // ================= main loop =================
    // entry invariants: hb[t&1]=c_t, acc=xw_t, xb[(t+1)&1]=x_{t+1} (t<63),
    //                   xld=x_{t+2} (t<62)
    #pragma unroll 1
    for (int t = 0; t < TSTEPS; ++t) {
        char* hcur = (t & 1) ? hb1 : hb0;
        char* hnxt = (t & 1) ? hb0 : hb1;
        char* xrd  = (t & 1) ? xb0 : xb1;   // x_{t+1}
        char* xwr  = (t & 1) ? xb1 : xb0;   // dest for x_{t+2}

        mm(hcur, whh);                       // acc = xw_t + c_t W_hh^T

        // c_{t+1} = relu(acc + bc)
        #pragma unroll
        for (int tc = 0; tc < 4; ++tc) {
            f32x4 v = acc[tc];
            #pragma unroll
            for (int j = 0; j < 4; ++j) v[j] = fmaxf(v[j] + bc[tc], 0.f);
            acc[tc] = v;
        }

        // LN partials: this wave's 64 cols -> psum[row][wv]
        {
            float s[4], q[4];
            #pragma unroll
            for (int j = 0; j < 4; ++j) {
                float a = 0.f, b = 0.f;
                #pragma unroll
                for (int tc = 0; tc < 4; ++tc) {
                    float v = acc[tc][j];
                    a += v; b += v * v;
                }
                s[j] = a; q[j] = b;
            }
            #pragma unroll
            for (int m = 1; m < 16; m <<= 1) {
                #pragma unroll
                for (int j = 0; j < 4; ++j) {
                    s[j] += __shfl_xor(s[j], m);
                    q[j] += __shfl_xor(q[j], m);
                }
            }
            if (l15 == 0) {
                #pragma unroll
                for (int j = 0; j < 4; ++j) {
                    const int row = l4*4 + j;
                    float2 w; w.x = s[j]; w.y = q[j];
                    *(float2*)(psum + (row*4 + wv)*2) = w;
                }
            }
        }

        if (t < 63) write_h(hnxt, false);    // c_{t+1} -> other h buffer

        bar_lgkm();                          // (A) psum + hnxt visible

        // parallel LN finalize: 4 lanes per row, wave 0
        if (tid < 64) {
            const int row = tid >> 2, p = tid & 3;
            const float2 v = *(const float2*)(psum + (row*4 + p)*2);
            float S = v.x, Q = v.y;
            S += __shfl_xor(S, 1); Q += __shfl_xor(Q, 1);
            S += __shfl_xor(S, 2); Q += __shfl_xor(Q, 2);
            if (p == 0) {
                const float mean = S * (1.f/256.f);
                const float var  = Q * (1.f/256.f) - mean * mean;
                float2 w; w.x = mean; w.y = rsqrtf(var + 1e-5f);
                *(float2*)(mrs + row*2) = w;
            }
        }
        if (t < 62) store_x(xwr);            // x_{t+2} -> xwr

        bar_lgkm();                          // (B) mrs visible; xwr staged

        if (t < 61) load_x(t + 3);           // issue next prefetch ASAP

        // normalize + store out[t]
        float* op = out + ((size_t)t * NTOT + n0) * HDIM;
        #pragma unroll
        for (int j = 0; j < 4; ++j) {
            const int row = l4*4 + j;
            const float2 ms = *(const float2*)(mrs + row*2);
            #pragma unroll
            for (int tc = 0; tc < 4; ++tc) {
                const int col = wv*64 + tc*16 + l15;
                op[row*HDIM + col] = (acc[tc][j] - ms.x) * ms.y * lw[tc] + lb[tc];
            }
        }

        if (t < 63) {
            zero_acc();
            mm(xrd, wih);                    // acc = xw_{t+1}
        }
    }
}

extern "C" void kernel_launch(void* const* d_in, const int* in_sizes, int n_in,
                              void* d_out, int out_size, void* d_ws, size_t ws_size,
                              hipStream_t stream) {
    const float* X   = (const float*)d_in[0];
    const float* Wih = (const float*)d_in[1];
    const float* Whh = (const float*)d_in[2];
    const float* bih = (const float*)d_in[3];
    const float* bhh = (const float*)d_in[4];
    const float* lnw = (const float*)d_in[5];
    const float* lnb = (const float*)d_in[6];
    float* out = (float*)d_out;

    rnn_ln_fused<<<dim3(NTOT / ROWS), dim3(NTHR), 0, stream>>>(
        X, Wih, Whh, bih, bhh, lnw, lnb, out);
}